// Round 6
// baseline (87.187 us; speedup 1.0000x reference)
//
#include <hip/hip_runtime.h>
#include <cstddef>

#define NWALKS 16384
#define TLEN   20
#define HDIM   128
#define WPB    32     // walks per block (2 tiles of 16 columns)
#define NTHR   512    // 8 waves

typedef __attribute__((ext_vector_type(8))) _Float16 f16x8;
typedef __attribute__((ext_vector_type(4))) _Float16 f16x4;
typedef __attribute__((ext_vector_type(2))) __fp16   h16x2;   // cvt_pkrtz result type
typedef __attribute__((ext_vector_type(4))) float    f32x4;

union H4 { f16x4 v; struct { h16x2 lo, hi; } p; };

// ---------------------------------------------------------------------------
// fold: Wc16 = f16(scale_row * (W_ih @ W_f)), Whh16 = f16(scale_row * W_hh),
// b_c = W_ih@b_f + b_ih (unscaled; scaled at load in gru_kernel).
//   r,z rows (0..255):  * -log2(e)   -> sigmoid(v) = rcp(1 + exp2(acc))
//   n  rows (256..383): * +2*log2(e) -> tanh(v)    = 1 - 2*rcp(exp2(acc)+1)
// ---------------------------------------------------------------------------
__global__ void fold_kernel(const float* __restrict__ W_f, const float* __restrict__ b_f,
                            const float* __restrict__ W_ih, const float* __restrict__ W_hh,
                            const float* __restrict__ b_ih,
                            _Float16* __restrict__ Wc16, _Float16* __restrict__ Whh16,
                            float* __restrict__ b_c) {
  const int r = blockIdx.x;    // 0..383
  const int i = threadIdx.x;   // 0..127
  const float scale = (r < 256) ? -1.4426950408889634f : 2.8853900817779268f;
  const float* wih = W_ih + r * HDIM;
  float acc = 0.f;
  for (int h = 0; h < HDIM; ++h) acc = fmaf(wih[h], W_f[h * HDIM + i], acc);
  Wc16[r * HDIM + i]  = (_Float16)(acc * scale);
  Whh16[r * HDIM + i] = (_Float16)(W_hh[r * HDIM + i] * scale);
  if (i == 0) {
    float bb = b_ih[r];
    for (int h = 0; h < HDIM; ++h) bb = fmaf(wih[h], b_f[h], bb);
    b_c[r] = bb;
  }
}

// ---------------------------------------------------------------------------
// Fused GRU, f16 MFMA, split-recurrence pipeline.
// Per step t: h-MFMAs for t (critical path, C-in = x-partials computed at
// t-1) + x-partial MFMAs for t+1 (barrier-independent slack).
// Wave wv owns gate columns [wv*16, wv*16+16); lane (g,l15) holds gates for
// j = wv*16+4g+{0..3}, walk = mt*16+l15. Weights persist in 96 regs.
// LDS x/h tiles XOR-swizzled on the 16B-chunk index (chunk ^= row&7).
// ---------------------------------------------------------------------------
__global__ __launch_bounds__(NTHR, 2)
void gru_kernel(const float* __restrict__ x, const int* __restrict__ walks,
                const _Float16* __restrict__ Wc16, const _Float16* __restrict__ Whh16,
                const float* __restrict__ b_c, const float* __restrict__ b_hh,
                float* __restrict__ out) {
  __shared__ _Float16 hbuf[2][WPB][HDIM];
  __shared__ _Float16 xbuf[2][WPB][HDIM];
  __shared__ int      nodes[TLEN][WPB];

  const int tid  = threadIdx.x;
  const int lane = tid & 63;
  const int wv   = tid >> 6;        // 0..7 : j-tile
  const int g    = lane >> 4;       // 0..3 : k-chunk / j-quad
  const int l15  = lane & 15;
  const int jw   = wv * 16 + l15;   // weight row for frag loads
  const int j0   = wv * 16 + 4 * g; // this lane's 4 j-columns
  const int walk0 = blockIdx.x * WPB;

  for (int idx = tid; idx < TLEN * WPB; idx += NTHR)
    nodes[idx >> 5][idx & 31] = walks[(walk0 + (idx & 31)) * TLEN + (idx >> 5)];
  for (int idx = tid; idx < WPB * HDIM; idx += NTHR)
    hbuf[0][0][idx] = (_Float16)0.f;   // zero fill: swizzle-invariant

  // ---- persistent weight fragments (A-operand), 96 VGPR ----
  f16x8 wrx[4], wrh[4], wzx[4], wzh[4], wnx[4], wnh[4];
#pragma unroll
  for (int kt = 0; kt < 4; ++kt) {
    const int koff = kt * 32 + g * 8;
    wrx[kt] = *(const f16x8*)(Wc16  + (size_t)(jw)       * HDIM + koff);
    wzx[kt] = *(const f16x8*)(Wc16  + (size_t)(128 + jw) * HDIM + koff);
    wnx[kt] = *(const f16x8*)(Wc16  + (size_t)(256 + jw) * HDIM + koff);
    wrh[kt] = *(const f16x8*)(Whh16 + (size_t)(jw)       * HDIM + koff);
    wzh[kt] = *(const f16x8*)(Whh16 + (size_t)(128 + jw) * HDIM + koff);
    wnh[kt] = *(const f16x8*)(Whh16 + (size_t)(256 + jw) * HDIM + koff);
  }
  // ---- biases (scaled to match weight row scaling), used as MFMA C-in ----
  const float NEG_L2E = -1.4426950408889634f;
  const float TWO_L2E =  2.8853900817779268f;
  const f32x4 br4  = NEG_L2E * (*(const f32x4*)&b_c[j0]       + *(const f32x4*)&b_hh[j0]);
  const f32x4 bz4  = NEG_L2E * (*(const f32x4*)&b_c[128 + j0] + *(const f32x4*)&b_hh[128 + j0]);
  const f32x4 bxn4 = TWO_L2E * (*(const f32x4*)&b_c[256 + j0]);
  const f32x4 bhn4 = TWO_L2E * (*(const f32x4*)&b_hh[256 + j0]);

  f32x4 hprev[2];
  hprev[0] = 0.f; hprev[1] = 0.f;

  // ---- swizzled LDS offsets (f16-element units) ----
  int voffs[4];
#pragma unroll
  for (int kt = 0; kt < 4; ++kt)
    voffs[kt] = l15 * HDIM + ((((kt * 4 + g) ^ (l15 & 7))) << 3);
  const int srow = tid >> 4;
  const int sc   = tid & 15;
  const int xw   = srow * HDIM + ((sc ^ (srow & 7)) << 3);
  const int hw   = l15 * HDIM + (((2 * wv + (g >> 1)) ^ (l15 & 7)) << 3) + ((g & 1) << 2);

  __syncthreads();   // nodes + hbuf[0] zeros visible

  // ---- prologue: stage x[0] -> xbuf[0]; load x[1] -> PA ----
  {
    const unsigned off0 = ((unsigned)nodes[0][srow] << 7) + sc * 8u;
    const f32x4 a = *(const f32x4*)(x + off0);
    const f32x4 b = *(const f32x4*)(x + off0 + 4);
    H4 lo, hi;
    lo.p.lo = __builtin_amdgcn_cvt_pkrtz(a.x, a.y);
    lo.p.hi = __builtin_amdgcn_cvt_pkrtz(a.z, a.w);
    hi.p.lo = __builtin_amdgcn_cvt_pkrtz(b.x, b.y);
    hi.p.hi = __builtin_amdgcn_cvt_pkrtz(b.z, b.w);
    *(f16x4*)(&xbuf[0][0][0] + xw)     = lo.v;
    *(f16x4*)(&xbuf[0][0][0] + xw + 4) = hi.v;
  }
  f32x4 PA0, PA1, PB0, PB1;
  {
    const unsigned off1 = ((unsigned)nodes[1][srow] << 7) + sc * 8u;
    PA0 = *(const f32x4*)(x + off1);
    PA1 = *(const f32x4*)(x + off1 + 4);
  }
  __syncthreads();   // xbuf[0] visible

  // ---- x-partials for t=0 from xbuf[0]; then write x[1]->xbuf[1] ----
  f32x4 PXRa[2], PXZa[2], PXNa[2], PXRb[2], PXZb[2], PXNb[2];
  {
    const _Float16* xb = &xbuf[0][0][0];
#pragma unroll
    for (int kt = 0; kt < 4; ++kt) {
      const f16x8 ax0 = *(const f16x8*)(xb + voffs[kt]);
      const f16x8 ax1 = *(const f16x8*)(xb + voffs[kt] + 16 * HDIM);
      PXRa[0] = __builtin_amdgcn_mfma_f32_16x16x32_f16(wrx[kt], ax0, kt ? PXRa[0] : br4,  0,0,0);
      PXRa[1] = __builtin_amdgcn_mfma_f32_16x16x32_f16(wrx[kt], ax1, kt ? PXRa[1] : br4,  0,0,0);
      PXZa[0] = __builtin_amdgcn_mfma_f32_16x16x32_f16(wzx[kt], ax0, kt ? PXZa[0] : bz4,  0,0,0);
      PXZa[1] = __builtin_amdgcn_mfma_f32_16x16x32_f16(wzx[kt], ax1, kt ? PXZa[1] : bz4,  0,0,0);
      PXNa[0] = __builtin_amdgcn_mfma_f32_16x16x32_f16(wnx[kt], ax0, kt ? PXNa[0] : bxn4, 0,0,0);
      PXNa[1] = __builtin_amdgcn_mfma_f32_16x16x32_f16(wnx[kt], ax1, kt ? PXNa[1] : bxn4, 0,0,0);
    }
  }
  {
    H4 lo, hi;
    lo.p.lo = __builtin_amdgcn_cvt_pkrtz(PA0.x, PA0.y);
    lo.p.hi = __builtin_amdgcn_cvt_pkrtz(PA0.z, PA0.w);
    hi.p.lo = __builtin_amdgcn_cvt_pkrtz(PA1.x, PA1.y);
    hi.p.hi = __builtin_amdgcn_cvt_pkrtz(PA1.z, PA1.w);
    *(f16x4*)(&xbuf[1][0][0] + xw)     = lo.v;
    *(f16x4*)(&xbuf[1][0][0] + xw + 4) = hi.v;
  }
  {
    const unsigned off2 = ((unsigned)nodes[2][srow] << 7) + sc * 8u;
    PB0 = *(const f32x4*)(x + off2);
    PB1 = *(const f32x4*)(x + off2 + 4);
  }
  __syncthreads();   // xbuf[1] visible; ready for t=0

// Step T: read h[t] from hbuf[HRD], write h[t+1] to hbuf[HWR];
// read x-frags for t+1 from xbuf[XRD]; write x[t+2] (regs S0,S1) to xbuf[XWR];
// load x[t+3] into L0,L1. PX* consumed (this step), QX* produced (next step).
#define STEP(T, XRD, XWR, HRD, HWR, L0, L1, S0, S1, PXR, PXZ, PXN, QXR, QXZ, QXN) \
  {                                                                               \
    const int tn = ((T) + 3 < TLEN) ? (T) + 3 : TLEN - 1;                         \
    const unsigned offn = ((unsigned)nodes[tn][srow] << 7) + sc * 8u;             \
    L0 = *(const f32x4*)(x + offn);                                               \
    L1 = *(const f32x4*)(x + offn + 4);                                           \
    const _Float16* xb = &xbuf[XRD][0][0];                                        \
    const _Float16* hb = &hbuf[HRD][0][0];                                        \
    f32x4 ah2[2];                                                                 \
    __builtin_amdgcn_s_setprio(1);                                                \
    /* h-MFMAs for step T (critical path): accumulate in place on PX */          \
    _Pragma("unroll")                                                             \
    for (int kt = 0; kt < 4; ++kt) {                                              \
      const f16x8 ah0 = *(const f16x8*)(hb + voffs[kt]);                          \
      const f16x8 ah1 = *(const f16x8*)(hb + voffs[kt] + 16 * HDIM);              \
      PXR[0] = __builtin_amdgcn_mfma_f32_16x16x32_f16(wrh[kt], ah0, PXR[0], 0,0,0); \
      PXR[1] = __builtin_amdgcn_mfma_f32_16x16x32_f16(wrh[kt], ah1, PXR[1], 0,0,0); \
      PXZ[0] = __builtin_amdgcn_mfma_f32_16x16x32_f16(wzh[kt], ah0, PXZ[0], 0,0,0); \
      PXZ[1] = __builtin_amdgcn_mfma_f32_16x16x32_f16(wzh[kt], ah1, PXZ[1], 0,0,0); \
      ah2[0] = __builtin_amdgcn_mfma_f32_16x16x32_f16(wnh[kt], ah0, kt ? ah2[0] : bhn4, 0,0,0); \
      ah2[1] = __builtin_amdgcn_mfma_f32_16x16x32_f16(wnh[kt], ah1, kt ? ah2[1] : bhn4, 0,0,0); \
    }                                                                             \
    /* x-partial MFMAs for step T+1 (barrier-independent slack) */                \
    _Pragma("unroll")                                                             \
    for (int kt = 0; kt < 4; ++kt) {                                              \
      const f16x8 ax0 = *(const f16x8*)(xb + voffs[kt]);                          \
      const f16x8 ax1 = *(const f16x8*)(xb + voffs[kt] + 16 * HDIM);              \
      QXR[0] = __builtin_amdgcn_mfma_f32_16x16x32_f16(wrx[kt], ax0, kt ? QXR[0] : br4,  0,0,0); \
      QXR[1] = __builtin_amdgcn_mfma_f32_16x16x32_f16(wrx[kt], ax1, kt ? QXR[1] : br4,  0,0,0); \
      QXZ[0] = __builtin_amdgcn_mfma_f32_16x16x32_f16(wzx[kt], ax0, kt ? QXZ[0] : bz4,  0,0,0); \
      QXZ[1] = __builtin_amdgcn_mfma_f32_16x16x32_f16(wzx[kt], ax1, kt ? QXZ[1] : bz4,  0,0,0); \
      QXN[0] = __builtin_amdgcn_mfma_f32_16x16x32_f16(wnx[kt], ax0, kt ? QXN[0] : bxn4, 0,0,0); \
      QXN[1] = __builtin_amdgcn_mfma_f32_16x16x32_f16(wnx[kt], ax1, kt ? QXN[1] : bxn4, 0,0,0); \
    }                                                                             \
    __builtin_amdgcn_s_setprio(0);                                                \
    /* stage x[T+2] into xbuf[XWR] */                                             \
    {                                                                             \
      H4 lo, hi;                                                                  \
      lo.p.lo = __builtin_amdgcn_cvt_pkrtz(S0.x, S0.y);                           \
      lo.p.hi = __builtin_amdgcn_cvt_pkrtz(S0.z, S0.w);                           \
      hi.p.lo = __builtin_amdgcn_cvt_pkrtz(S1.x, S1.y);                           \
      hi.p.hi = __builtin_amdgcn_cvt_pkrtz(S1.z, S1.w);                           \
      *(f16x4*)(&xbuf[XWR][0][0] + xw)     = lo.v;                                \
      *(f16x4*)(&xbuf[XWR][0][0] + xw + 4) = hi.v;                                \
    }                                                                             \
    /* gates (lane-local) + h writeback */                                        \
    _Pragma("unroll")                                                             \
    for (int mt = 0; mt < 2; ++mt) {                                              \
      f32x4 hn;                                                                   \
      _Pragma("unroll")                                                           \
      for (int r = 0; r < 4; ++r) {                                               \
        const float rv = __builtin_amdgcn_rcpf(1.f + __builtin_amdgcn_exp2f(PXR[mt][r])); \
        const float zv = __builtin_amdgcn_rcpf(1.f + __builtin_amdgcn_exp2f(PXZ[mt][r])); \
        const float en = __builtin_amdgcn_exp2f(fmaf(rv, ah2[mt][r], PXN[mt][r])); \
        const float nv = fmaf(-2.f, __builtin_amdgcn_rcpf(en + 1.f), 1.f);        \
        hn[r] = fmaf(zv, hprev[mt][r] - nv, nv);                                  \
      }                                                                           \
      hprev[mt] = hn;                                                             \
      H4 hp;                                                                      \
      hp.p.lo = __builtin_amdgcn_cvt_pkrtz(hn[0], hn[1]);                         \
      hp.p.hi = __builtin_amdgcn_cvt_pkrtz(hn[2], hn[3]);                         \
      *(f16x4*)(&hbuf[HWR][0][0] + hw + mt * 16 * HDIM) = hp.v;                   \
    }                                                                             \
    __syncthreads();                                                              \
  }

#pragma unroll 1
  for (int tt = 0; tt < TLEN; tt += 2) {
    STEP(tt,     1, 0, 0, 1, PA0, PA1, PB0, PB1, PXRa, PXZa, PXNa, PXRb, PXZb, PXNb)
    STEP(tt + 1, 0, 1, 1, 0, PB0, PB1, PA0, PA1, PXRb, PXZb, PXNb, PXRa, PXZa, PXNa)
  }
#undef STEP

  // ---- final h: lane holds j0..j0+3 for walks l15, 16+l15 ----
#pragma unroll
  for (int mt = 0; mt < 2; ++mt) {
    float4 o = make_float4(hprev[mt][0], hprev[mt][1], hprev[mt][2], hprev[mt][3]);
    *(float4*)&out[(size_t)(walk0 + mt * 16 + l15) * HDIM + j0] = o;
  }
}

extern "C" void kernel_launch(void* const* d_in, const int* in_sizes, int n_in,
                              void* d_out, int out_size, void* d_ws, size_t ws_size,
                              hipStream_t stream) {
  const float* x     = (const float*)d_in[0];
  const int*   walks = (const int*)  d_in[1];
  const float* W_f   = (const float*)d_in[2];
  const float* b_f   = (const float*)d_in[3];
  const float* W_ih  = (const float*)d_in[4];
  const float* W_hh  = (const float*)d_in[5];
  const float* b_ih  = (const float*)d_in[6];
  const float* b_hh  = (const float*)d_in[7];
  float* out = (float*)d_out;

  _Float16* Wc16  = (_Float16*)d_ws;                 // 384*128 f16
  _Float16* Whh16 = Wc16 + 384 * HDIM;               // 384*128 f16
  float*    b_c   = (float*)(Whh16 + 384 * HDIM);    // 384 f32

  fold_kernel<<<3 * HDIM, HDIM, 0, stream>>>(W_f, b_f, W_ih, W_hh, b_ih, Wc16, Whh16, b_c);
  gru_kernel<<<NWALKS / WPB, NTHR, 0, stream>>>(x, walks, Wc16, Whh16, b_c, b_hh, out);
}

// Round 7
// 84.325 us; speedup vs baseline: 1.0339x; 1.0339x over previous
//
#include <hip/hip_runtime.h>
#include <cstddef>

#define NWALKS 16384
#define TLEN   20
#define HDIM   128
#define WPB    32     // walks per block (2 tiles of 16 columns)
#define NTHR   512    // 8 waves

typedef __attribute__((ext_vector_type(8))) _Float16 f16x8;
typedef __attribute__((ext_vector_type(4))) _Float16 f16x4;
typedef __attribute__((ext_vector_type(2))) __fp16   h16x2;   // cvt_pkrtz result type
typedef __attribute__((ext_vector_type(4))) float    f32x4;

union H4 { f16x4 v; struct { h16x2 lo, hi; } p; };

// ---------------------------------------------------------------------------
// fold: Wc16 = f16(scale_row * (W_ih @ W_f)), Whh16 = f16(scale_row * W_hh),
// b_c = W_ih@b_f + b_ih (unscaled; scaled at load in gru_kernel).
//   r,z rows (0..255):  * -log2(e)   -> sigmoid(v) = rcp(1 + exp2(acc))
//   n  rows (256..383): * +2*log2(e) -> tanh(v)    = 1 - 2*rcp(exp2(acc)+1)
// ---------------------------------------------------------------------------
__global__ void fold_kernel(const float* __restrict__ W_f, const float* __restrict__ b_f,
                            const float* __restrict__ W_ih, const float* __restrict__ W_hh,
                            const float* __restrict__ b_ih,
                            _Float16* __restrict__ Wc16, _Float16* __restrict__ Whh16,
                            float* __restrict__ b_c) {
  const int r = blockIdx.x;    // 0..383
  const int i = threadIdx.x;   // 0..127
  const float scale = (r < 256) ? -1.4426950408889634f : 2.8853900817779268f;
  const float* wih = W_ih + r * HDIM;
  float acc = 0.f;
  for (int h = 0; h < HDIM; ++h) acc = fmaf(wih[h], W_f[h * HDIM + i], acc);
  Wc16[r * HDIM + i]  = (_Float16)(acc * scale);
  Whh16[r * HDIM + i] = (_Float16)(W_hh[r * HDIM + i] * scale);
  if (i == 0) {
    float bb = b_ih[r];
    for (int h = 0; h < HDIM; ++h) bb = fmaf(wih[h], b_f[h], bb);
    b_c[r] = bb;
  }
}

// ---------------------------------------------------------------------------
// Fused GRU, f16 MFMA. Wave wv owns gate columns [wv*16, wv*16+16); lane
// (g,l15) holds gates for j = wv*16+4g+{0..3}, walk = mt*16+l15. Weights
// persist in 96 regs; biases enter via MFMA C-in on kt==0.
// Round-7 schedule changes vs round-5:
//  * raw s_barrier + lgkmcnt(0) only -> x-gather prefetch loads stay in
//    flight ACROSS the barrier (no vmcnt(0) drain per step)       [T4]
//  * sched_group_barrier {DS_READ x4 -> MFMA x12} with 1-kt lookahead
//    breaks the per-barrier LDS read burst                        [T19]
// ---------------------------------------------------------------------------
__global__ __launch_bounds__(NTHR, 2)
void gru_kernel(const float* __restrict__ x, const int* __restrict__ walks,
                const _Float16* __restrict__ Wc16, const _Float16* __restrict__ Whh16,
                const float* __restrict__ b_c, const float* __restrict__ b_hh,
                float* __restrict__ out) {
  __shared__ _Float16 hbuf[2][WPB][HDIM];
  __shared__ _Float16 xbuf[2][WPB][HDIM];
  __shared__ int      nodes[TLEN][WPB];

  const int tid  = threadIdx.x;
  const int lane = tid & 63;
  const int wv   = tid >> 6;        // 0..7 : j-tile
  const int g    = lane >> 4;       // 0..3 : k-chunk / j-quad
  const int l15  = lane & 15;
  const int jw   = wv * 16 + l15;   // weight row for frag loads
  const int j0   = wv * 16 + 4 * g; // this lane's 4 j-columns
  const int walk0 = blockIdx.x * WPB;

  for (int idx = tid; idx < TLEN * WPB; idx += NTHR)
    nodes[idx >> 5][idx & 31] = walks[(walk0 + (idx & 31)) * TLEN + (idx >> 5)];
  for (int idx = tid; idx < WPB * HDIM; idx += NTHR)
    hbuf[0][0][idx] = (_Float16)0.f;   // zero fill: swizzle-invariant

  // ---- persistent weight fragments (A-operand), 96 VGPR ----
  f16x8 wrx[4], wrh[4], wzx[4], wzh[4], wnx[4], wnh[4];
#pragma unroll
  for (int kt = 0; kt < 4; ++kt) {
    const int koff = kt * 32 + g * 8;
    wrx[kt] = *(const f16x8*)(Wc16  + (size_t)(jw)       * HDIM + koff);
    wzx[kt] = *(const f16x8*)(Wc16  + (size_t)(128 + jw) * HDIM + koff);
    wnx[kt] = *(const f16x8*)(Wc16  + (size_t)(256 + jw) * HDIM + koff);
    wrh[kt] = *(const f16x8*)(Whh16 + (size_t)(jw)       * HDIM + koff);
    wzh[kt] = *(const f16x8*)(Whh16 + (size_t)(128 + jw) * HDIM + koff);
    wnh[kt] = *(const f16x8*)(Whh16 + (size_t)(256 + jw) * HDIM + koff);
  }
  // ---- biases (scaled to match weight row scaling), used as MFMA C-in ----
  const float NEG_L2E = -1.4426950408889634f;
  const float TWO_L2E =  2.8853900817779268f;
  const f32x4 br4  = NEG_L2E * (*(const f32x4*)&b_c[j0]       + *(const f32x4*)&b_hh[j0]);
  const f32x4 bz4  = NEG_L2E * (*(const f32x4*)&b_c[128 + j0] + *(const f32x4*)&b_hh[128 + j0]);
  const f32x4 bxn4 = TWO_L2E * (*(const f32x4*)&b_c[256 + j0]);
  const f32x4 bhn4 = TWO_L2E * (*(const f32x4*)&b_hh[256 + j0]);

  f32x4 hprev[2];
  hprev[0] = 0.f; hprev[1] = 0.f;

  // ---- swizzled LDS offsets (f16-element units) ----
  int voffs[4];
#pragma unroll
  for (int kt = 0; kt < 4; ++kt)
    voffs[kt] = l15 * HDIM + ((((kt * 4 + g) ^ (l15 & 7))) << 3);
  const int srow = tid >> 4;
  const int sc   = tid & 15;
  const int xw   = srow * HDIM + ((sc ^ (srow & 7)) << 3);
  const int hw   = l15 * HDIM + (((2 * wv + (g >> 1)) ^ (l15 & 7)) << 3) + ((g & 1) << 2);

  __syncthreads();   // nodes + hbuf[0] zeros visible

  // ---- prologue: stage x[0] into xbuf[0]; load x[1] into regs ----
  {
    const unsigned off0 = ((unsigned)nodes[0][srow] << 7) + sc * 8u;
    const f32x4 a = *(const f32x4*)(x + off0);
    const f32x4 b = *(const f32x4*)(x + off0 + 4);
    H4 lo, hi;
    lo.p.lo = __builtin_amdgcn_cvt_pkrtz(a.x, a.y);
    lo.p.hi = __builtin_amdgcn_cvt_pkrtz(a.z, a.w);
    hi.p.lo = __builtin_amdgcn_cvt_pkrtz(b.x, b.y);
    hi.p.hi = __builtin_amdgcn_cvt_pkrtz(b.z, b.w);
    *(f16x4*)(&xbuf[0][0][0] + xw)     = lo.v;
    *(f16x4*)(&xbuf[0][0][0] + xw + 4) = hi.v;
  }
  f32x4 PA0, PA1, PB0, PB1;
  {
    const unsigned off1 = ((unsigned)nodes[1][srow] << 7) + sc * 8u;
    PA0 = *(const f32x4*)(x + off1);
    PA1 = *(const f32x4*)(x + off1 + 4);
  }
  __syncthreads();   // xbuf[0] + hbuf[0] visible

#define STEP(T, CUR, NXT, P0, P1, N0, N1)                                         \
  {                                                                               \
    /* 1. issue gather for x[T+2]; stays in flight across the raw barrier */      \
    const int tn = ((T) + 2 < TLEN) ? (T) + 2 : TLEN - 1;                         \
    const unsigned offn = ((unsigned)nodes[tn][srow] << 7) + sc * 8u;             \
    N0 = *(const f32x4*)(x + offn);                                               \
    N1 = *(const f32x4*)(x + offn + 4);                                           \
    /* 2. MFMAs, read/compute pipelined one kt ahead; bias C-in on kt==0 */       \
    const _Float16* xb = &xbuf[CUR][0][0];                                        \
    const _Float16* hb = &hbuf[CUR][0][0];                                        \
    f32x4 ar[2], az[2], an[2], ah2[2];                                            \
    f16x8 AX0[4], AX1[4], AH0[4], AH1[4];                                         \
    AX0[0] = *(const f16x8*)(xb + voffs[0]);                                      \
    AX1[0] = *(const f16x8*)(xb + voffs[0] + 16 * HDIM);                          \
    AH0[0] = *(const f16x8*)(hb + voffs[0]);                                      \
    AH1[0] = *(const f16x8*)(hb + voffs[0] + 16 * HDIM);                          \
    __builtin_amdgcn_sched_group_barrier(0x100, 4, 0);  /* DS_READ x4 (kt=0) */   \
    __builtin_amdgcn_s_setprio(1);                                                \
    _Pragma("unroll")                                                             \
    for (int kt = 0; kt < 4; ++kt) {                                              \
      if (kt < 3) {                                                               \
        AX0[kt + 1] = *(const f16x8*)(xb + voffs[kt + 1]);                        \
        AX1[kt + 1] = *(const f16x8*)(xb + voffs[kt + 1] + 16 * HDIM);            \
        AH0[kt + 1] = *(const f16x8*)(hb + voffs[kt + 1]);                        \
        AH1[kt + 1] = *(const f16x8*)(hb + voffs[kt + 1] + 16 * HDIM);            \
      }                                                                           \
      ar[0]  = __builtin_amdgcn_mfma_f32_16x16x32_f16(wrx[kt], AX0[kt], kt ? ar[0]  : br4,  0,0,0); \
      ar[1]  = __builtin_amdgcn_mfma_f32_16x16x32_f16(wrx[kt], AX1[kt], kt ? ar[1]  : br4,  0,0,0); \
      ar[0]  = __builtin_amdgcn_mfma_f32_16x16x32_f16(wrh[kt], AH0[kt], ar[0],  0,0,0); \
      ar[1]  = __builtin_amdgcn_mfma_f32_16x16x32_f16(wrh[kt], AH1[kt], ar[1],  0,0,0); \
      az[0]  = __builtin_amdgcn_mfma_f32_16x16x32_f16(wzx[kt], AX0[kt], kt ? az[0]  : bz4,  0,0,0); \
      az[1]  = __builtin_amdgcn_mfma_f32_16x16x32_f16(wzx[kt], AX1[kt], kt ? az[1]  : bz4,  0,0,0); \
      az[0]  = __builtin_amdgcn_mfma_f32_16x16x32_f16(wzh[kt], AH0[kt], az[0],  0,0,0); \
      az[1]  = __builtin_amdgcn_mfma_f32_16x16x32_f16(wzh[kt], AH1[kt], az[1],  0,0,0); \
      an[0]  = __builtin_amdgcn_mfma_f32_16x16x32_f16(wnx[kt], AX0[kt], kt ? an[0]  : bxn4, 0,0,0); \
      an[1]  = __builtin_amdgcn_mfma_f32_16x16x32_f16(wnx[kt], AX1[kt], kt ? an[1]  : bxn4, 0,0,0); \
      ah2[0] = __builtin_amdgcn_mfma_f32_16x16x32_f16(wnh[kt], AH0[kt], kt ? ah2[0] : bhn4, 0,0,0); \
      ah2[1] = __builtin_amdgcn_mfma_f32_16x16x32_f16(wnh[kt], AH1[kt], kt ? ah2[1] : bhn4, 0,0,0); \
      if (kt < 3) __builtin_amdgcn_sched_group_barrier(0x100, 4, 0); /* next-kt reads */ \
      __builtin_amdgcn_sched_group_barrier(0x8, 12, 0);              /* this-kt MFMAs */ \
    }                                                                             \
    __builtin_amdgcn_s_setprio(0);                                                \
    /* 3. write x[T+1] (loaded last step) into the other buffer */                \
    {                                                                             \
      H4 lo, hi;                                                                  \
      lo.p.lo = __builtin_amdgcn_cvt_pkrtz(P0.x, P0.y);                           \
      lo.p.hi = __builtin_amdgcn_cvt_pkrtz(P0.z, P0.w);                           \
      hi.p.lo = __builtin_amdgcn_cvt_pkrtz(P1.x, P1.y);                           \
      hi.p.hi = __builtin_amdgcn_cvt_pkrtz(P1.z, P1.w);                           \
      *(f16x4*)(&xbuf[NXT][0][0] + xw)     = lo.v;                                \
      *(f16x4*)(&xbuf[NXT][0][0] + xw + 4) = hi.v;                                \
    }                                                                             \
    /* 4. gates (lane-local, scaled-exp2 forms) + h writeback (b64) */            \
    _Pragma("unroll")                                                             \
    for (int mt = 0; mt < 2; ++mt) {                                              \
      f32x4 hn;                                                                   \
      _Pragma("unroll")                                                           \
      for (int r = 0; r < 4; ++r) {                                               \
        const float rv = __builtin_amdgcn_rcpf(1.f + __builtin_amdgcn_exp2f(ar[mt][r])); \
        const float zv = __builtin_amdgcn_rcpf(1.f + __builtin_amdgcn_exp2f(az[mt][r])); \
        const float en = __builtin_amdgcn_exp2f(fmaf(rv, ah2[mt][r], an[mt][r])); \
        const float nv = fmaf(-2.f, __builtin_amdgcn_rcpf(en + 1.f), 1.f);        \
        hn[r] = fmaf(zv, hprev[mt][r] - nv, nv);                                  \
      }                                                                           \
      hprev[mt] = hn;                                                             \
      H4 hp;                                                                      \
      hp.p.lo = __builtin_amdgcn_cvt_pkrtz(hn[0], hn[1]);                         \
      hp.p.hi = __builtin_amdgcn_cvt_pkrtz(hn[2], hn[3]);                         \
      *(f16x4*)(&hbuf[NXT][0][0] + hw + mt * 16 * HDIM) = hp.v;                   \
    }                                                                             \
    /* 5. raw barrier: LDS drain only; global prefetch stays in flight */         \
    __builtin_amdgcn_sched_barrier(0);                                            \
    asm volatile("s_waitcnt lgkmcnt(0)" ::: "memory");                            \
    __builtin_amdgcn_s_barrier();                                                 \
    __builtin_amdgcn_sched_barrier(0);                                            \
  }

#pragma unroll 1
  for (int tt = 0; tt < TLEN; tt += 2) {
    STEP(tt,     0, 1, PA0, PA1, PB0, PB1)
    STEP(tt + 1, 1, 0, PB0, PB1, PA0, PA1)
  }
#undef STEP

  // ---- final h: lane holds j0..j0+3 for walks l15, 16+l15 ----
#pragma unroll
  for (int mt = 0; mt < 2; ++mt) {
    float4 o = make_float4(hprev[mt][0], hprev[mt][1], hprev[mt][2], hprev[mt][3]);
    *(float4*)&out[(size_t)(walk0 + mt * 16 + l15) * HDIM + j0] = o;
  }
}

extern "C" void kernel_launch(void* const* d_in, const int* in_sizes, int n_in,
                              void* d_out, int out_size, void* d_ws, size_t ws_size,
                              hipStream_t stream) {
  const float* x     = (const float*)d_in[0];
  const int*   walks = (const int*)  d_in[1];
  const float* W_f   = (const float*)d_in[2];
  const float* b_f   = (const float*)d_in[3];
  const float* W_ih  = (const float*)d_in[4];
  const float* W_hh  = (const float*)d_in[5];
  const float* b_ih  = (const float*)d_in[6];
  const float* b_hh  = (const float*)d_in[7];
  float* out = (float*)d_out;

  _Float16* Wc16  = (_Float16*)d_ws;                 // 384*128 f16
  _Float16* Whh16 = Wc16 + 384 * HDIM;               // 384*128 f16
  float*    b_c   = (float*)(Whh16 + 384 * HDIM);    // 384 f32

  fold_kernel<<<3 * HDIM, HDIM, 0, stream>>>(W_f, b_f, W_ih, W_hh, b_ih, Wc16, Whh16, b_c);
  gru_kernel<<<NWALKS / WPB, NTHR, 0, stream>>>(x, walks, Wc16, Whh16, b_c, b_hh, out);
}